// Round 2
// baseline (488.350 us; speedup 1.0000x reference)
//
#include <hip/hip_runtime.h>
#include <hip/hip_bf16.h>

typedef short short8 __attribute__((ext_vector_type(8)));
typedef float f32x4 __attribute__((ext_vector_type(4)));
typedef unsigned short ushort8_t __attribute__((ext_vector_type(8)));

#define O_CH 128
#define I_CH 128
#define HW 112
#define PLANE (HW * HW)      // 12544
#define NCOL 114             // 112 cols + 2 halo
#define CH 64                // channels per half
#define NROWS 4              // staged input rows (2 output rows + halo)

__device__ __forceinline__ unsigned short f2bf(float f) {
  union { float f; unsigned u; } v; v.f = f;
  unsigned r = v.u + 0x7FFFu + ((v.u >> 16) & 1u);   // RNE
  return (unsigned short)(r >> 16);
}

__device__ __forceinline__ unsigned pk2bf(float a, float b) {
  return (unsigned)f2bf(a) | ((unsigned)f2bf(b) << 16);
}

__global__ void wsynth_kernel(const float* __restrict__ core,
                              const float* __restrict__ periph,
                              const float* __restrict__ thr,
                              const float* __restrict__ scale,
                              unsigned short* __restrict__ Wb) {
  int idx = blockIdx.x * blockDim.x + threadIdx.x;   // o*128 + i
  if (idx >= O_CH * I_CH) return;
  int o = idx >> 7;
  float c = core[idx];
  float s = scale[0];
  float g = 1.0f / (1.0f + __expf(-s * (fabsf(c) - thr[o])));
#pragma unroll
  for (int tap = 0; tap < 9; ++tap) {
    float p  = (tap == 4) ? 1.0f : periph[tap < 4 ? tap : tap - 1];
    float gg = (tap == 4) ? 1.0f : g;
    Wb[tap * (O_CH * I_CH) + idx] = f2bf(c * p * gg);   // layout [tap][o][i]
  }
}

__global__ __launch_bounds__(256, 2)
void conv_kernel(const float* __restrict__ X,
                 const unsigned short* __restrict__ Wb,
                 float* __restrict__ Out) {
  // [row 0..3][col 0..113][ch 0..63] bf16, XOR-swizzled: byte ^= (col&7)<<4
  __shared__ unsigned short Xs[NROWS * NCOL * CH];   // 58,368 B -> 2 WGs/CU
  char* lds = (char*)Xs;

  // XCD-chunked swizzle: 1792 WGs = 8 XCDs x 224 contiguous logical ids
  const int bid = blockIdx.x;
  const int L = (bid & 7) * 224 + (bid >> 3);
  const int b = L / 56;
  const int pair = L - b * 56;
  const int y0 = pair * 2;          // output rows y0, y0+1

  const int t   = threadIdx.x;
  const int wv  = t >> 6;           // wave 0..3
  const int l   = t & 63;
  const int ln  = l & 15;           // MFMA frag lane (col / m-row)
  const int lk4 = l >> 4;           // k-slice 0..3
  const int mi  = wv & 1;           // o-half (64 o's)
  const int yi  = wv >> 1;          // output row within pair

  f32x4 acc[4][7];
#pragma unroll
  for (int fm = 0; fm < 4; ++fm)
#pragma unroll
    for (int nf = 0; nf < 7; ++nf)
      acc[fm][nf] = (f32x4)0.0f;

  for (int h = 0; h < 2; ++h) {
    if (h) __syncthreads();   // finish compute on previous half before overwrite

    // ---- stage rows y0-1 .. y0+2, channels [h*64, h*64+64), bf16, swizzled ----
#pragma unroll
    for (int r = 0; r < NROWS; ++r) {
      const int row = y0 - 1 + r;
      const bool rok = (row >= 0) && (row < HW);
      const float* srcb = X + ((size_t)(b * I_CH + h * CH) * HW + row) * HW;
#pragma unroll
      for (int cc = 0; cc < 2; ++cc) {
        const int col  = cc * 64 + l;       // staged col index (input col + 1)
        const int icol = col - 1;
        const bool cok = (col < NCOL);
        const bool vok = rok && (icol >= 0) && (icol < HW);
        const float* s0 = srcb + icol;
#pragma unroll
        for (int gi = 0; gi < 2; ++gi) {
          const int g = wv * 2 + gi;        // ch-group 0..7 (8 ch each)
          const float* sp = s0 + (size_t)g * 8 * PLANE;
          float v0 = 0.f, v1 = 0.f, v2 = 0.f, v3 = 0.f;
          float v4 = 0.f, v5 = 0.f, v6 = 0.f, v7 = 0.f;
          if (vok) {
            v0 = sp[0 * PLANE]; v1 = sp[1 * PLANE];
            v2 = sp[2 * PLANE]; v3 = sp[3 * PLANE];
            v4 = sp[4 * PLANE]; v5 = sp[5 * PLANE];
            v6 = sp[6 * PLANE]; v7 = sp[7 * PLANE];
          }
          if (cok) {
            union { ushort8_t s; unsigned u[4]; } pk;
            pk.u[0] = pk2bf(v0, v1);
            pk.u[1] = pk2bf(v2, v3);
            pk.u[2] = pk2bf(v4, v5);
            pk.u[3] = pk2bf(v6, v7);
            const int byteoff = (((r * NCOL + col) * CH + g * 8) * 2) ^ ((col & 7) << 4);
            *reinterpret_cast<ushort8_t*>(lds + byteoff) = pk.s;
          }
        }
      }
    }
    __syncthreads();

    // ---- compute: 9 taps x 2 k-chunks; A from L2 (regs), B from LDS ----
#pragma unroll
    for (int r = 0; r < 3; ++r) {
      const int rowoff = (yi + r) * NCOL;
#pragma unroll
      for (int dx = 0; dx < 3; ++dx) {
        const int tap = r * 3 + dx;
        const int colbase = dx + ln;                 // + nf*16
        const int xorv = (colbase & 7) << 4;         // (col&7) independent of nf
#pragma unroll
        for (int ci = 0; ci < 2; ++ci) {
          const unsigned short* wp = Wb + tap * (O_CH * I_CH)
                                   + (mi * 64 + ln) * I_CH
                                   + h * CH + ci * 32 + lk4 * 8;
          short8 a0 = *reinterpret_cast<const short8*>(wp);
          short8 a1 = *reinterpret_cast<const short8*>(wp + 16 * I_CH);
          short8 a2 = *reinterpret_cast<const short8*>(wp + 32 * I_CH);
          short8 a3 = *reinterpret_cast<const short8*>(wp + 48 * I_CH);
          const int baddr = ((rowoff + colbase) * CH + ci * 32 + lk4 * 8) * 2;
#pragma unroll
          for (int nf = 0; nf < 7; ++nf) {
            short8 bb = *reinterpret_cast<const short8*>(
                lds + ((baddr + nf * 16 * CH * 2) ^ xorv));
            acc[0][nf] = __builtin_amdgcn_mfma_f32_16x16x32_bf16(a0, bb, acc[0][nf], 0, 0, 0);
            acc[1][nf] = __builtin_amdgcn_mfma_f32_16x16x32_bf16(a1, bb, acc[1][nf], 0, 0, 0);
            acc[2][nf] = __builtin_amdgcn_mfma_f32_16x16x32_bf16(a2, bb, acc[2][nf], 0, 0, 0);
            acc[3][nf] = __builtin_amdgcn_mfma_f32_16x16x32_bf16(a3, bb, acc[3][nf], 0, 0, 0);
          }
        }
      }
    }
  }

  // ---- epilogue: C/D map col=lane&15, row=(lane>>4)*4+j ----
  float* outp = Out + (size_t)b * O_CH * PLANE + (size_t)(y0 + yi) * HW;
#pragma unroll
  for (int fm = 0; fm < 4; ++fm) {
#pragma unroll
    for (int j = 0; j < 4; ++j) {
      const int o = mi * 64 + fm * 16 + lk4 * 4 + j;
      float* po = outp + (size_t)o * PLANE;
#pragma unroll
      for (int nf = 0; nf < 7; ++nf) {
        po[nf * 16 + ln] = acc[fm][nf][j];
      }
    }
  }
}

extern "C" void kernel_launch(void* const* d_in, const int* in_sizes, int n_in,
                              void* d_out, int out_size, void* d_ws, size_t ws_size,
                              hipStream_t stream) {
  const float* x      = (const float*)d_in[0];
  const float* core   = (const float*)d_in[1];
  const float* periph = (const float*)d_in[2];
  const float* thr    = (const float*)d_in[3];
  const float* scale  = (const float*)d_in[4];
  unsigned short* Wb  = (unsigned short*)d_ws;   // 9*128*128*2 = 294,912 B

  wsynth_kernel<<<(O_CH * I_CH + 255) / 256, 256, 0, stream>>>(core, periph, thr, scale, Wb);

  const int grid = 32 * (HW / 2);   // one WG per (batch, output-row pair) = 1792
  conv_kernel<<<grid, 256, 0, stream>>>(x, Wb, (float*)d_out);
}

// Round 3
// 412.969 us; speedup vs baseline: 1.1825x; 1.1825x over previous
//
#include <hip/hip_runtime.h>

typedef short short8 __attribute__((ext_vector_type(8)));
typedef float f32x4 __attribute__((ext_vector_type(4)));
typedef unsigned short ushort8_t __attribute__((ext_vector_type(8)));

#define O_CH 128
#define I_CH 128
#define HW 112
#define PLANE (HW * HW)      // 12544
#define NCOL 114             // 112 cols + 2 halo
#define CH 64                // channels per half; col stride = 128 B

__device__ __forceinline__ unsigned short f2bf(float f) {
  union { float f; unsigned u; } v; v.f = f;
  unsigned r = v.u + 0x7FFFu + ((v.u >> 16) & 1u);   // RNE
  return (unsigned short)(r >> 16);
}
__device__ __forceinline__ unsigned pk2bf(float a, float b) {
  return (unsigned)f2bf(a) | ((unsigned)f2bf(b) << 16);
}

__global__ void wsynth_kernel(const float* __restrict__ core,
                              const float* __restrict__ periph,
                              const float* __restrict__ thr,
                              const float* __restrict__ scale,
                              unsigned short* __restrict__ Wb) {
  int idx = blockIdx.x * blockDim.x + threadIdx.x;   // o*128 + i
  if (idx >= O_CH * I_CH) return;
  int o = idx >> 7;
  float c = core[idx];
  float s = scale[0];
  float g = 1.0f / (1.0f + __expf(-s * (fabsf(c) - thr[o])));
#pragma unroll
  for (int tap = 0; tap < 9; ++tap) {
    float p  = (tap == 4) ? 1.0f : periph[tap < 4 ? tap : tap - 1];
    float gg = (tap == 4) ? 1.0f : g;
    Wb[tap * (O_CH * I_CH) + idx] = f2bf(c * p * gg);   // layout [tap][o][i]
  }
}

__global__ __launch_bounds__(256, 3)
void conv_kernel(const float* __restrict__ X,
                 const unsigned short* __restrict__ Wb,
                 float* __restrict__ Out) {
  // [row 0..2][col 0..113][ch 0..63] bf16, swizzled: byte ^= (col&7)<<4
  __shared__ unsigned short Xs[3 * NCOL * CH];   // 43,776 B -> 3 WGs/CU
  char* lds = (char*)Xs;

  // XCD-chunked swizzle: 3584 = 8 XCDs x 448 contiguous logical ids
  const int bid = blockIdx.x;
  const int L = (bid & 7) * 448 + (bid >> 3);
  const int b = L / HW;
  const int y = L - b * HW;

  const int t   = threadIdx.x;
  const int wv  = t >> 6;           // wave 0..3 -> o quarter
  const int l   = t & 63;
  const int ln  = l & 15;           // MFMA frag lane
  const int lk4 = l >> 4;           // k-slice 0..3

  // staging coords
  const int col  = t & 127;         // staged col (input col + 1)
  const int i2   = t >> 7;          // 0..1 -> 32-ch block
  const int icol = col - 1;
  const bool cok = (col < NCOL);

  f32x4 acc[2][7];
#pragma unroll
  for (int mr = 0; mr < 2; ++mr)
#pragma unroll
    for (int nf = 0; nf < 7; ++nf)
      acc[mr][nf] = (f32x4)0.0f;

  // per-thread invariant LDS read base (bytes): ln*128 + lk4*16
  const int rdbase = ln * 128 + lk4 * 16;

  for (int h = 0; h < 2; ++h) {
    if (h) __syncthreads();   // finish compute on previous half before overwrite

    // prefetch tap 0 A-fragments (no LDS dependency; completes across barrier)
    const unsigned short* wh = Wb + (wv * 32 + ln) * I_CH + lk4 * 8 + h * CH;
    short8 c00 = *reinterpret_cast<const short8*>(wh);
    short8 c10 = *reinterpret_cast<const short8*>(wh + 16 * I_CH);
    short8 c01 = *reinterpret_cast<const short8*>(wh + 32);
    short8 c11 = *reinterpret_cast<const short8*>(wh + 32 + 16 * I_CH);

    // ---- stage rows y-1..y+1, channels [h*64, h*64+64) as bf16, swizzled ----
#pragma unroll
    for (int r = 0; r < 3; ++r) {
      const int row = y + r - 1;
      const bool vok = (row >= 0) && (row < HW) && (icol >= 0) && (icol < HW);
      const float* sp0 = X + ((size_t)(b * I_CH + h * CH + i2 * 32) * HW + row) * HW + icol;
#pragma unroll
      for (int q8 = 0; q8 < 4; ++q8) {       // 8 channels per iteration
        const float* sp = sp0 + (size_t)q8 * 8 * PLANE;
        float v0 = 0.f, v1 = 0.f, v2 = 0.f, v3 = 0.f;
        float v4 = 0.f, v5 = 0.f, v6 = 0.f, v7 = 0.f;
        if (vok) {
          v0 = sp[0 * PLANE]; v1 = sp[1 * PLANE];
          v2 = sp[2 * PLANE]; v3 = sp[3 * PLANE];
          v4 = sp[4 * PLANE]; v5 = sp[5 * PLANE];
          v6 = sp[6 * PLANE]; v7 = sp[7 * PLANE];
        }
        if (cok) {
          union { ushort8_t s; unsigned u[4]; } pk;
          pk.u[0] = pk2bf(v0, v1);
          pk.u[1] = pk2bf(v2, v3);
          pk.u[2] = pk2bf(v4, v5);
          pk.u[3] = pk2bf(v6, v7);
          const int byteoff = (((r * NCOL + col) * CH + i2 * 32 + q8 * 8) * 2)
                              ^ ((col & 7) << 4);
          *reinterpret_cast<ushort8_t*>(lds + byteoff) = pk.s;
        }
      }
    }
    __syncthreads();

    // ---- compute: 9 taps, A pipelined one tap ahead ----
#pragma unroll
    for (int tap = 0; tap < 9; ++tap) {
      short8 n00, n10, n01, n11;
      if (tap < 8) {
        const unsigned short* wn = wh + (tap + 1) * (O_CH * I_CH);
        n00 = *reinterpret_cast<const short8*>(wn);
        n10 = *reinterpret_cast<const short8*>(wn + 16 * I_CH);
        n01 = *reinterpret_cast<const short8*>(wn + 32);
        n11 = *reinterpret_cast<const short8*>(wn + 32 + 16 * I_CH);
      }
      const int r  = tap / 3;
      const int dx = tap % 3;
      const int xorv = ((dx + ln) & 7) << 4;
      const int taddr = rdbase + (r * NCOL + dx) * 128;
#pragma unroll
      for (int ci = 0; ci < 2; ++ci) {
        const short8 a0 = ci ? c01 : c00;
        const short8 a1 = ci ? c11 : c10;
#pragma unroll
        for (int nf = 0; nf < 7; ++nf) {
          short8 bb = *reinterpret_cast<const short8*>(
              lds + ((taddr + ci * 64 + nf * 16 * 128) ^ xorv));
          acc[0][nf] = __builtin_amdgcn_mfma_f32_16x16x32_bf16(a0, bb, acc[0][nf], 0, 0, 0);
          acc[1][nf] = __builtin_amdgcn_mfma_f32_16x16x32_bf16(a1, bb, acc[1][nf], 0, 0, 0);
        }
      }
      if (tap < 8) { c00 = n00; c10 = n10; c01 = n01; c11 = n11; }
    }
  }

  // ---- epilogue: C/D map col=lane&15, row=(lane>>4)*4+j; nontemporal stores ----
  const int obase = wv * 32 + lk4 * 4;
  float* outp = Out + (size_t)b * O_CH * PLANE + (size_t)y * HW;
#pragma unroll
  for (int mr = 0; mr < 2; ++mr) {
#pragma unroll
    for (int j = 0; j < 4; ++j) {
      const int o = obase + mr * 16 + j;
      float* po = outp + (size_t)o * PLANE;
#pragma unroll
      for (int nf = 0; nf < 7; ++nf) {
        __builtin_nontemporal_store(acc[mr][nf][j], po + nf * 16 + ln);
      }
    }
  }
}

extern "C" void kernel_launch(void* const* d_in, const int* in_sizes, int n_in,
                              void* d_out, int out_size, void* d_ws, size_t ws_size,
                              hipStream_t stream) {
  const float* x      = (const float*)d_in[0];
  const float* core   = (const float*)d_in[1];
  const float* periph = (const float*)d_in[2];
  const float* thr    = (const float*)d_in[3];
  const float* scale  = (const float*)d_in[4];
  unsigned short* Wb  = (unsigned short*)d_ws;   // 9*128*128*2 = 294,912 B

  wsynth_kernel<<<(O_CH * I_CH + 255) / 256, 256, 0, stream>>>(core, periph, thr, scale, Wb);

  const int grid = 32 * HW;   // one WG per (batch, output row) = 3584
  conv_kernel<<<grid, 256, 0, stream>>>(x, Wb, (float*)d_out);
}